// Round 9
// baseline (362.948 us; speedup 1.0000x reference)
//
#include <hip/hip_runtime.h>

// VQ-VAE quantization: z [16384 x 512] f32, codebook [8192 x 512] f32.
// out = concat(z_st [16384*512] f32, vq_loss [1] f32).
//
// R4: MX-fp8 (e4m3, K=128 scaled MFMA) GEMM; packed (dist|idx) u32 argmin.
// R8: XCD remap + dbuf. R10/R11: 128x256 blocks — still spilled (scaled-MFMA
// acc lives in arch VGPRs, unlike bf16 MFMA's AGPRs; 64-reg acc/thread
// doesn't fit the 128 cap with staging addressing).
// R12 (this): per-thread state cut in half. R5's proven flow (8192 blocks,
// 128x128 tile, XCD remap, dbuf prefetch-before-compute, 2 barriers/dt)
// but 512 thr / 8 waves, wave tile 64x32 -> acc = 32 VGPR, peak liveness
// ~85 << 128 cap -> spill-free (R9 measured VGPR=100 with this tiling).
// LDS 66KB -> 2 blocks/CU, 16 waves/CU.

#define M_ROWS 16384
#define K_CODES 8192
#define DIM 512
#define BM 128
#define BN 128
#define BK 128                 // fp8 bytes per K-step (one 16x16x128 MFMA)
#define NT (K_CODES / BN)      // 64 ktiles
#define OUT0_SIZE (M_ROWS * DIM)
#define GB_BLOCKS 1024

typedef int   i32x8 __attribute__((ext_vector_type(8)));
typedef float f32x4 __attribute__((ext_vector_type(4)));

template <bool HI>
__device__ __forceinline__ int pk8(float a, float b, int old) {
    return __builtin_amdgcn_cvt_pk_fp8_f32(a, b, old, HI);
}

__device__ __forceinline__ void gload_lds(const unsigned char* g, unsigned char* l) {
    __builtin_amdgcn_global_load_lds((const __attribute__((address_space(1))) void*)g,
                                     (__attribute__((address_space(3))) void*)l, 16, 0, 0);
}

// ---- kernel 1: fused converts ------------------------------------------
__global__ __launch_bounds__(256) void convert_all(
    const float* __restrict__ z, const float* __restrict__ cb,
    unsigned char* __restrict__ z8, unsigned char* __restrict__ cb8,
    float* __restrict__ enorm, unsigned int* __restrict__ counter)
{
    const int tid = threadIdx.x;
    if (blockIdx.x == 0 && tid == 0) *counter = 0;   // for gather_out's last-block
    if (blockIdx.x < K_CODES / 4) {
        const int w = tid >> 6, lane = tid & 63;
        const int row = blockIdx.x * 4 + w;
        const float* src = cb + (size_t)row * DIM + lane * 8;
        float4 a = *(const float4*)(src);
        float4 b = *(const float4*)(src + 4);
        float ns = a.x * a.x + a.y * a.y + a.z * a.z + a.w * a.w
                 + b.x * b.x + b.y * b.y + b.z * b.z + b.w * b.w;
        const float S = 8192.0f;                 // exact power of 2
        int lo = 0, hi = 0;
        lo = pk8<false>(a.x * S, a.y * S, lo); lo = pk8<true>(a.z * S, a.w * S, lo);
        hi = pk8<false>(b.x * S, b.y * S, hi); hi = pk8<true>(b.z * S, b.w * S, hi);
        *(int2*)(cb8 + (size_t)row * DIM + lane * 8) = make_int2(lo, hi);
        for (int m = 32; m; m >>= 1) ns += __shfl_down(ns, m, 64);
        if (lane == 0) enorm[row] = S * ns;      // 8192 * ||e||^2 (f32-exact norm)
    } else {
        size_t i = ((size_t)(blockIdx.x - K_CODES / 4) * 256 + tid) * 8;
        float4 a = *(const float4*)(z + i);
        float4 b = *(const float4*)(z + i + 4);
        int lo = 0, hi = 0;
        lo = pk8<false>(a.x, a.y, lo); lo = pk8<true>(a.z, a.w, lo);
        hi = pk8<false>(b.x, b.y, hi); hi = pk8<true>(b.z, b.w, hi);
        *(int2*)(z8 + i) = make_int2(lo, hi);
    }
}

// ---- kernel 2: MX-fp8 GEMM (128x128, 8 waves) + packed-argmin ----------
__global__ __launch_bounds__(512, 2) void gemm_argmin(
    const unsigned char* __restrict__ z8, const unsigned char* __restrict__ cbb,
    const float* __restrict__ enorm, unsigned int* __restrict__ candV)
{
    __shared__ alignas(32) unsigned char As[2][BM * BK];   // 32 KB dbuf
    __shared__ alignas(32) unsigned char Bs[2][BN * BK];   // 32 KB dbuf
    __shared__ unsigned int cU[BM][4];                     //  2 KB

    const int tid = threadIdx.x;
    const int lane = tid & 63;
    const int w = tid >> 6;             // 0..7
    // XCD remap (R5-proven): b&7 = XCD; XCD owns mtiles [xcd*16,xcd*16+16)
    // (1MB A slice, L2-hot); ktile advances every 128 blocks.
    const int b = blockIdx.x;
    const int xcd = b & 7;
    const int idx = b >> 3;             // 0..1023
    const int ktile = idx >> 4;         // 0..63
    const int mtile = xcd * 16 + (idx & 15);
    const int mbase = mtile * BM;
    const int nbase = ktile * BN;

    const int rA = lane >> 3;           // row within 8-row chunk
    const int jG = ((lane & 7) ^ rA) * 16;  // pre-swizzled global 16B chunk
    const int quad = lane >> 4;
    const int l15 = lane & 15;
    const int sw = l15 & 7;
    const int wr = (w >> 2) * 64;       // wave row half: 0/64
    const int wc = (w & 3) * 32;        // wave col quarter: 0/32/64/96
    // Chunks c0=(2q)^sw, c1=c0^1 = one aligned 32B block (R3-proven: the
    // per-lane half-swap is identical for A and B -> dot product exact).
    const int t32 = ((quad << 1) ^ (sw & 6)) * 16;

    float es0 = enorm[nbase + wc + l15];
    float es1 = enorm[nbase + wc + 16 + l15];

    f32x4 acc[8];
#pragma unroll
    for (int i = 0; i < 8; ++i) acc[i] = (f32x4){0.f, 0.f, 0.f, 0.f};

    // 512 threads: chunk c = w*2+i covers 0..15 per matrix (1KB each).
#define STAGE(buf, dt_) do {                                                  \
    _Pragma("unroll")                                                         \
    for (int i_ = 0; i_ < 2; ++i_) {                                          \
        int c_ = w * 2 + i_;                                                  \
        int row_ = c_ * 8 + rA;                                               \
        int col_ = (dt_) * BK + jG;                                           \
        gload_lds(z8 + (size_t)(mbase + row_) * DIM + col_,                   \
                  As[buf] + c_ * 1024 + lane * 16);                           \
        gload_lds(cbb + (size_t)(nbase + row_) * DIM + col_,                  \
                  Bs[buf] + c_ * 1024 + lane * 16);                           \
    } } while (0)

    STAGE(0, 0);
    __syncthreads();   // vmcnt(0) drained before barrier -> buf0 ready

#pragma unroll
    for (int dt = 0; dt < 4; ++dt) {
        const int cur = dt & 1;
        if (dt < 3) STAGE(cur ^ 1, dt + 1);   // prefetch overlaps this compute
        i32x8 bf0 = *(const i32x8*)(Bs[cur] + (wc + l15) * BK + t32);
        i32x8 bf1 = *(const i32x8*)(Bs[cur] + (wc + 16 + l15) * BK + t32);
#pragma unroll
        for (int rf = 0; rf < 4; ++rf) {
            i32x8 a = *(const i32x8*)(As[cur] + (wr + rf * 16 + l15) * BK + t32);
            acc[rf * 2 + 0] = __builtin_amdgcn_mfma_scale_f32_16x16x128_f8f6f4(
                a, bf0, acc[rf * 2 + 0], 0, 0, 0, 0x7F7F7F7F, 0, 0x7F7F7F7F);
            acc[rf * 2 + 1] = __builtin_amdgcn_mfma_scale_f32_16x16x128_f8f6f4(
                a, bf1, acc[rf * 2 + 1], 0, 0, 0, 0x7F7F7F7F, 0, 0x7F7F7F7F);
        }
        __syncthreads();   // reads done; prefetched buffer landed
    }
#undef STAGE

    // epilogue: per-row argmin over this tile's 128 cols.
    // C/D layout: col = lane&15, row = quad*4 + reg.
    // Packed key: monotone-uint(dist), low 13 bits = global code index.
#pragma unroll
    for (int rf = 0; rf < 4; ++rf) {
#pragma unroll
        for (int r = 0; r < 4; ++r) {
            float d0 = fmaf(-2.0f, acc[rf * 2 + 0][r], es0);
            float d1 = fmaf(-2.0f, acc[rf * 2 + 1][r], es1);
            float bv = d1 < d0 ? d1 : d0;           // strict <: low col on tie
            int col = d1 < d0 ? wc + 16 + l15 : wc + l15;
            unsigned u = __builtin_bit_cast(unsigned, bv);
            u ^= ((unsigned)(((int)u) >> 31)) | 0x80000000u;
            unsigned key = (u & 0xFFFFE000u) | (unsigned)(nbase + col);
#pragma unroll
            for (int sh = 1; sh < 16; sh <<= 1) {
                unsigned o = __shfl_xor(key, sh, 64);
                key = o < key ? o : key;
            }
            if (l15 == 0) cU[wr + rf * 16 + quad * 4 + r][w & 3] = key;
        }
    }
    __syncthreads();
    if (tid < BM) {
        unsigned k0 = cU[tid][0], k1 = cU[tid][1];
        unsigned k2 = cU[tid][2], k3 = cU[tid][3];
        unsigned ka = k0 < k1 ? k0 : k1;
        unsigned kb = k2 < k3 ? k2 : k3;
        candV[(size_t)ktile * M_ROWS + mbase + tid] = ka < kb ? ka : kb;
    }
}

// ---- kernel 3: candidate-reduce + gather + ST output + fused loss ------
// 4 waves/block, wave owns a row/iter: umin over 64 packed candidates
// (lane = ktile), then 128 float4 slots. Last block reduces partials.
__global__ __launch_bounds__(256) void gather_out(
    const float* __restrict__ z, const float* __restrict__ cb,
    const unsigned int* __restrict__ candV, float* __restrict__ out,
    float* __restrict__ partials, unsigned int* __restrict__ counter)
{
    __shared__ float red[4];
    __shared__ unsigned int lastflag;
    const int tid = threadIdx.x;
    const int w = tid >> 6, lane = tid & 63;
    float lsum = 0.f;
#pragma unroll
    for (int it = 0; it < M_ROWS / (GB_BLOCKS * 4); ++it) {
        int row = (it * GB_BLOCKS + blockIdx.x) * 4 + w;
        unsigned key = candV[(size_t)lane * M_ROWS + row];
#pragma unroll
        for (int m = 1; m < 64; m <<= 1) {
            unsigned o = __shfl_xor(key, m, 64);
            key = o < key ? o : key;
        }
        int k = (int)(key & 8191u);
#pragma unroll
        for (int j = 0; j < 2; ++j) {
            int slot = lane + j * 64;
            float4 zv = ((const float4*)(z + (size_t)row * DIM))[slot];
            float4 cv = ((const float4*)(cb + (size_t)k * DIM))[slot];
            float dx = cv.x - zv.x, dy = cv.y - zv.y;
            float dz2 = cv.z - zv.z, dw = cv.w - zv.w;
            float4 o = {zv.x + dx, zv.y + dy, zv.z + dz2, zv.w + dw};  // z + sg(zq-z)
            ((float4*)(out + (size_t)row * DIM))[slot] = o;
            lsum += dx * dx + dy * dy + dz2 * dz2 + dw * dw;
        }
    }
    for (int m = 32; m; m >>= 1) lsum += __shfl_down(lsum, m, 64);
    if (lane == 0) red[w] = lsum;
    __syncthreads();
    if (tid == 0) {
        float t = (red[0] + red[1]) + (red[2] + red[3]);
        __hip_atomic_store(&partials[blockIdx.x], t,
                           __ATOMIC_RELAXED, __HIP_MEMORY_SCOPE_AGENT);
        unsigned prev = __hip_atomic_fetch_add(counter, 1u,
                           __ATOMIC_ACQ_REL, __HIP_MEMORY_SCOPE_AGENT);
        lastflag = (prev == GB_BLOCKS - 1) ? 1u : 0u;
    }
    __syncthreads();
    if (lastflag) {
        float s = 0.f;
#pragma unroll
        for (int i = 0; i < GB_BLOCKS / 256; ++i)
            s += __hip_atomic_load(&partials[i * 256 + tid],
                                   __ATOMIC_RELAXED, __HIP_MEMORY_SCOPE_AGENT);
        for (int m = 32; m; m >>= 1) s += __shfl_down(s, m, 64);
        if ((tid & 63) == 0) red[tid >> 6] = s;
        __syncthreads();
        if (tid == 0)
            out[OUT0_SIZE] = ((red[0] + red[1]) + (red[2] + red[3]))
                             * (1.1f / (float)OUT0_SIZE);
    }
}

extern "C" void kernel_launch(void* const* d_in, const int* in_sizes, int n_in,
                              void* d_out, int out_size, void* d_ws, size_t ws_size,
                              hipStream_t stream) {
    const float* z = (const float*)d_in[0];     // 16*1024*512
    const float* cb = (const float*)d_in[1];    // 8192*512
    float* out = (float*)d_out;                 // 8388608 + 1
    char* ws = (char*)d_ws;

    // ws layout (bytes)
    unsigned char* z8      = (unsigned char*)(ws);            //  8,388,608
    unsigned char* cb8     = (unsigned char*)(ws + 8388608);  //  4,194,304
    float* enorm           = (float*)(ws + 12582912);         //     32,768
    unsigned int* candV    = (unsigned int*)(ws + 12615680);  //  4,194,304
    float* partials        = (float*)(ws + 16809984);         //      4,096
    unsigned int* counter  = (unsigned int*)(ws + 16814080);  //          4

    convert_all<<<K_CODES / 4 + M_ROWS * DIM / 2048, 256, 0, stream>>>(
        z, cb, z8, cb8, enorm, counter);
    gemm_argmin<<<NT * (M_ROWS / BM), 512, 0, stream>>>(z8, cb8, enorm, candV);
    gather_out<<<GB_BLOCKS, 256, 0, stream>>>(z, cb, candV, out, partials, counter);
}

// Round 10
// 252.327 us; speedup vs baseline: 1.4384x; 1.4384x over previous
//
#include <hip/hip_runtime.h>

// VQ-VAE quantization: z [16384 x 512] f32, codebook [8192 x 512] f32.
// out = concat(z_st [16384*512] f32, vq_loss [1] f32).
//
// R4: MX-fp8 (e4m3, K=128 scaled MFMA) GEMM; packed (dist|idx) u32 argmin.
// R8(=155µs best): 256thr/4-wave 64x64 wave tiles, XCD remap, dbuf.
// R9/R10/R11/R12: 512-thr and wide-tile variants all SLOWER (LDS-read
// amplification + 8-wave convoy), independent of spill. Reverted.
// R13 (this): R8-best shape exactly, minus its 53MB scratch spill:
//  - #pragma unroll 1 on dt loop (full unroll was hoisting stage addrs
//    across iterations past the 128-VGPR cap);
//  - B-frag hoist 4 -> 2 (two cf half-passes, A reloaded per half):
//    peak liveness ~105 < 128. Costs 4 extra A-frag LDS reads/dt (hidden
//    under the ~1100cyc MFMA phase).
//  - last-block loss fusion REVERTED (acq-rel atomic tail cost ~35µs
//    vs separate 3µs reduce kernel): partials + reduce_loss.

#define M_ROWS 16384
#define K_CODES 8192
#define DIM 512
#define BM 128
#define BN 128
#define BK 128                 // fp8 bytes per K-step (one 16x16x128 MFMA)
#define NT (K_CODES / BN)      // 64 ktiles
#define OUT0_SIZE (M_ROWS * DIM)
#define GB_BLOCKS 1024

typedef int   i32x8 __attribute__((ext_vector_type(8)));
typedef float f32x4 __attribute__((ext_vector_type(4)));

template <bool HI>
__device__ __forceinline__ int pk8(float a, float b, int old) {
    return __builtin_amdgcn_cvt_pk_fp8_f32(a, b, old, HI);
}

__device__ __forceinline__ void gload_lds(const unsigned char* g, unsigned char* l) {
    __builtin_amdgcn_global_load_lds((const __attribute__((address_space(1))) void*)g,
                                     (__attribute__((address_space(3))) void*)l, 16, 0, 0);
}

// ---- kernel 1: fused converts ------------------------------------------
__global__ __launch_bounds__(256) void convert_all(
    const float* __restrict__ z, const float* __restrict__ cb,
    unsigned char* __restrict__ z8, unsigned char* __restrict__ cb8,
    float* __restrict__ enorm)
{
    const int tid = threadIdx.x;
    if (blockIdx.x < K_CODES / 4) {
        const int w = tid >> 6, lane = tid & 63;
        const int row = blockIdx.x * 4 + w;
        const float* src = cb + (size_t)row * DIM + lane * 8;
        float4 a = *(const float4*)(src);
        float4 b = *(const float4*)(src + 4);
        float ns = a.x * a.x + a.y * a.y + a.z * a.z + a.w * a.w
                 + b.x * b.x + b.y * b.y + b.z * b.z + b.w * b.w;
        const float S = 8192.0f;                 // exact power of 2
        int lo = 0, hi = 0;
        lo = pk8<false>(a.x * S, a.y * S, lo); lo = pk8<true>(a.z * S, a.w * S, lo);
        hi = pk8<false>(b.x * S, b.y * S, hi); hi = pk8<true>(b.z * S, b.w * S, hi);
        *(int2*)(cb8 + (size_t)row * DIM + lane * 8) = make_int2(lo, hi);
        for (int m = 32; m; m >>= 1) ns += __shfl_down(ns, m, 64);
        if (lane == 0) enorm[row] = S * ns;      // 8192 * ||e||^2 (f32-exact norm)
    } else {
        size_t i = ((size_t)(blockIdx.x - K_CODES / 4) * 256 + tid) * 8;
        float4 a = *(const float4*)(z + i);
        float4 b = *(const float4*)(z + i + 4);
        int lo = 0, hi = 0;
        lo = pk8<false>(a.x, a.y, lo); lo = pk8<true>(a.z, a.w, lo);
        hi = pk8<false>(b.x, b.y, hi); hi = pk8<true>(b.z, b.w, hi);
        *(int2*)(z8 + i) = make_int2(lo, hi);
    }
}

// ---- kernel 2: MX-fp8 GEMM (128x128, 4 waves) + packed-argmin ----------
__global__ __launch_bounds__(256, 2) void gemm_argmin(
    const unsigned char* __restrict__ z8, const unsigned char* __restrict__ cbb,
    const float* __restrict__ enorm, unsigned int* __restrict__ candV)
{
    __shared__ alignas(32) unsigned char As[2 * BM * BK];  // 32 KB dbuf
    __shared__ alignas(32) unsigned char Bs[2 * BN * BK];  // 32 KB dbuf
    __shared__ float Es[BN];
    __shared__ unsigned int cU[BM][2];

    const int tid = threadIdx.x;
    const int lane = tid & 63;
    const int w = tid >> 6;             // 0..3
    // XCD remap: b&7 = XCD; XCD owns mtiles [xcd*16,xcd*16+16) (1MB A
    // slice, L2-hot); ktile advances every 128 blocks.
    const int b = blockIdx.x;
    const int xcd = b & 7;
    const int idx = b >> 3;             // 0..1023
    const int ktile = idx >> 4;         // 0..63
    const int mtile = xcd * 16 + (idx & 15);
    const int mbase = mtile * BM;
    const int nbase = ktile * BN;

    if (tid < BN) Es[tid] = enorm[nbase + tid];

    f32x4 acc[16];
#pragma unroll
    for (int i = 0; i < 16; ++i) acc[i] = (f32x4){0.f, 0.f, 0.f, 0.f};

    const int rA = lane >> 3;           // row within 8-row chunk
    const int jG = ((lane & 7) ^ rA) * 16;  // pre-swizzled global 16B chunk
    const int quad = lane >> 4;
    const int l15 = lane & 15;
    const int sw = l15 & 7;
    const int rw = (w >> 1) * 64;       // wave row quadrant
    const int cw = (w & 1) * 64;        // wave col quadrant
    // Chunks c0=(2q)^sw, c1=c0^1 = one aligned 32B block (R3-proven: the
    // per-lane half-swap is identical for A and B -> dot product exact).
    const int t32 = ((quad << 1) ^ (sw & 6)) * 16;

#define STAGE(buf, dt_) do {                                                  \
    _Pragma("unroll")                                                         \
    for (int i_ = 0; i_ < 4; ++i_) {                                          \
        int c_ = w * 4 + i_;                                                  \
        int row_ = c_ * 8 + rA;                                               \
        int col_ = (dt_) * BK + jG;                                           \
        gload_lds(z8 + (size_t)(mbase + row_) * DIM + col_,                   \
                  As + (buf) * (BM * BK) + c_ * 1024 + lane * 16);            \
        gload_lds(cbb + (size_t)(nbase + row_) * DIM + col_,                  \
                  Bs + (buf) * (BN * BK) + c_ * 1024 + lane * 16);            \
    } } while (0)

    STAGE(0, 0);
    __syncthreads();   // compiler drains vmcnt(0) before barrier -> buf0 ready

#pragma unroll 1
    for (int dt = 0; dt < 4; ++dt) {
        const int cur = dt & 1;
        if (dt < 3) STAGE(cur ^ 1, dt + 1);   // prefetch overlaps this compute
        const unsigned char* Ab = As + cur * (BM * BK);
        const unsigned char* Bb = Bs + cur * (BN * BK);
#pragma unroll
        for (int h = 0; h < 2; ++h) {         // 2 B frags live at a time
            i32x8 bf0 = *(const i32x8*)(Bb + (cw + (h * 2 + 0) * 16 + l15) * BK + t32);
            i32x8 bf1 = *(const i32x8*)(Bb + (cw + (h * 2 + 1) * 16 + l15) * BK + t32);
#pragma unroll
            for (int rf = 0; rf < 4; ++rf) {
                i32x8 a = *(const i32x8*)(Ab + (rw + rf * 16 + l15) * BK + t32);
                acc[rf * 4 + h * 2 + 0] = __builtin_amdgcn_mfma_scale_f32_16x16x128_f8f6f4(
                    a, bf0, acc[rf * 4 + h * 2 + 0],
                    0, 0, 0, 0x7F7F7F7F, 0, 0x7F7F7F7F);
                acc[rf * 4 + h * 2 + 1] = __builtin_amdgcn_mfma_scale_f32_16x16x128_f8f6f4(
                    a, bf1, acc[rf * 4 + h * 2 + 1],
                    0, 0, 0, 0x7F7F7F7F, 0, 0x7F7F7F7F);
            }
        }
        __syncthreads();   // reads done; prefetched buffer landed
    }
#undef STAGE

    // epilogue: per-row argmin over this tile's 128 cols.
    // C/D layout: col = lane&15, row = quad*4 + reg.
    // Packed key: monotone-uint(dist), low 13 bits = global code index.
    float es[4];
#pragma unroll
    for (int cf = 0; cf < 4; ++cf) es[cf] = Es[cw + cf * 16 + l15];

#pragma unroll
    for (int rf = 0; rf < 4; ++rf) {
#pragma unroll
        for (int r = 0; r < 4; ++r) {
            float bv = 3.4e38f; int bi = 0;
#pragma unroll
            for (int cf = 0; cf < 4; ++cf) {
                int col = cw + cf * 16 + l15;
                float dist = fmaf(-2.0f, acc[rf * 4 + cf][r], es[cf]);
                if (dist < bv) { bv = dist; bi = col; }  // strict <: low col on tie
            }
            unsigned u = __builtin_bit_cast(unsigned, bv);
            u ^= ((unsigned)(((int)u) >> 31)) | 0x80000000u;
            unsigned key = (u & 0xFFFFE000u) | (unsigned)(nbase + bi);
#pragma unroll
            for (int m = 1; m < 16; m <<= 1) {
                unsigned o = __shfl_xor(key, m, 64);
                key = o < key ? o : key;
            }
            if (l15 == 0) cU[rw + rf * 16 + quad * 4 + r][w & 1] = key;
        }
    }
    __syncthreads();
    if (tid < BM) {
        unsigned k0 = cU[tid][0], k1 = cU[tid][1];
        // [ktile][row] layout: 128 consecutive ints per block = full lines
        candV[(size_t)ktile * M_ROWS + mbase + tid] = k0 < k1 ? k0 : k1;
    }
}

// ---- kernel 3: candidate-reduce + gather + ST output -------------------
// 4 waves/block, wave owns a row/iter: umin over the 64 packed candidates
// (lane = ktile), then 128 float4 slots. Loss partial per block.
__global__ __launch_bounds__(256) void gather_out(
    const float* __restrict__ z, const float* __restrict__ cb,
    const unsigned int* __restrict__ candV, float* __restrict__ out,
    float* __restrict__ partials)
{
    __shared__ float red[4];
    const int tid = threadIdx.x;
    const int w = tid >> 6, lane = tid & 63;
    float lsum = 0.f;
#pragma unroll
    for (int it = 0; it < M_ROWS / (GB_BLOCKS * 4); ++it) {
        int row = (it * GB_BLOCKS + blockIdx.x) * 4 + w;
        unsigned key = candV[(size_t)lane * M_ROWS + row];
#pragma unroll
        for (int m = 1; m < 64; m <<= 1) {
            unsigned o = __shfl_xor(key, m, 64);
            key = o < key ? o : key;
        }
        int k = (int)(key & 8191u);
#pragma unroll
        for (int j = 0; j < 2; ++j) {
            int slot = lane + j * 64;
            float4 zv = ((const float4*)(z + (size_t)row * DIM))[slot];
            float4 cv = ((const float4*)(cb + (size_t)k * DIM))[slot];
            float dx = cv.x - zv.x, dy = cv.y - zv.y;
            float dz2 = cv.z - zv.z, dw = cv.w - zv.w;
            float4 o = {zv.x + dx, zv.y + dy, zv.z + dz2, zv.w + dw};  // z + sg(zq-z)
            ((float4*)(out + (size_t)row * DIM))[slot] = o;
            lsum += dx * dx + dy * dy + dz2 * dz2 + dw * dw;
        }
    }
    for (int m = 32; m; m >>= 1) lsum += __shfl_down(lsum, m, 64);
    if (lane == 0) red[w] = lsum;
    __syncthreads();
    if (tid == 0) partials[blockIdx.x] = (red[0] + red[1]) + (red[2] + red[3]);
}

// ---- kernel 4: final loss reduction (1024 partials -> scalar) ----------
__global__ __launch_bounds__(256) void reduce_loss(
    const float* __restrict__ partials, float* __restrict__ lossOut)
{
    __shared__ float red[4];
    const int tid = threadIdx.x;
    float s = 0.f;
#pragma unroll
    for (int i = 0; i < GB_BLOCKS / 256; ++i) s += partials[i * 256 + tid];
    for (int m = 32; m; m >>= 1) s += __shfl_down(s, m, 64);
    if ((tid & 63) == 0) red[tid >> 6] = s;
    __syncthreads();
    if (tid == 0)
        lossOut[0] = ((red[0] + red[1]) + (red[2] + red[3])) * (1.1f / (float)OUT0_SIZE);
}

extern "C" void kernel_launch(void* const* d_in, const int* in_sizes, int n_in,
                              void* d_out, int out_size, void* d_ws, size_t ws_size,
                              hipStream_t stream) {
    const float* z = (const float*)d_in[0];     // 16*1024*512
    const float* cb = (const float*)d_in[1];    // 8192*512
    float* out = (float*)d_out;                 // 8388608 + 1
    char* ws = (char*)d_ws;

    // ws layout (bytes)
    unsigned char* z8   = (unsigned char*)(ws);               //  8,388,608
    unsigned char* cb8  = (unsigned char*)(ws + 8388608);     //  4,194,304
    float* enorm        = (float*)(ws + 12582912);            //     32,768
    unsigned int* candV = (unsigned int*)(ws + 12615680);     //  4,194,304
    float* partials     = (float*)(ws + 16809984);            //      4,096

    convert_all<<<K_CODES / 4 + M_ROWS * DIM / 2048, 256, 0, stream>>>(
        z, cb, z8, cb8, enorm);
    gemm_argmin<<<NT * (M_ROWS / BM), 256, 0, stream>>>(z8, cb8, enorm, candV);
    gather_out<<<GB_BLOCKS, 256, 0, stream>>>(z, cb, candV, out, partials);
    reduce_loss<<<1, 256, 0, stream>>>(partials, out + OUT0_SIZE);
}

// Round 11
// 252.210 us; speedup vs baseline: 1.4391x; 1.0005x over previous
//
#include <hip/hip_runtime.h>

// VQ-VAE quantization: z [16384 x 512] f32, codebook [8192 x 512] f32.
// out = concat(z_st [16384*512] f32, vq_loss [1] f32).
//
// R4: MX-fp8 (e4m3, K=128 scaled MFMA) GEMM; packed (dist|idx) u32 argmin.
// R13 (=148.5µs gemm, 252 total best): 256thr/4-wave 64x64 wave tiles,
// XCD remap, dbuf, unroll-1 + 2-B-frag hoist (spill-free: WRITE 4KB).
// R14 (this): counted-vmcnt schedule (T4) + setprio (T5), same shape.
// __syncthreads in the K-loop drained the just-issued prefetch every
// iteration (vmcnt(0) before s_barrier) — ~50% of wall was stall. Now:
// issue STAGE(next); s_waitcnt vmcnt(8) [= previous stage only]; raw
// s_barrier; MFMA (setprio 1); raw s_barrier. Prefetch stays in flight
// across barriers. Uniform 8 loads/thread/STAGE keeps per-wave vmcnt
// bookkeeping exact; prologue __syncthreads zeroes it.

#define M_ROWS 16384
#define K_CODES 8192
#define DIM 512
#define BM 128
#define BN 128
#define BK 128                 // fp8 bytes per K-step (one 16x16x128 MFMA)
#define NT (K_CODES / BN)      // 64 ktiles
#define OUT0_SIZE (M_ROWS * DIM)
#define GB_BLOCKS 1024

typedef int   i32x8 __attribute__((ext_vector_type(8)));
typedef float f32x4 __attribute__((ext_vector_type(4)));

template <bool HI>
__device__ __forceinline__ int pk8(float a, float b, int old) {
    return __builtin_amdgcn_cvt_pk_fp8_f32(a, b, old, HI);
}

__device__ __forceinline__ void gload_lds(const unsigned char* g, unsigned char* l) {
    __builtin_amdgcn_global_load_lds((const __attribute__((address_space(1))) void*)g,
                                     (__attribute__((address_space(3))) void*)l, 16, 0, 0);
}

// ---- kernel 1: fused converts ------------------------------------------
__global__ __launch_bounds__(256) void convert_all(
    const float* __restrict__ z, const float* __restrict__ cb,
    unsigned char* __restrict__ z8, unsigned char* __restrict__ cb8,
    float* __restrict__ enorm)
{
    const int tid = threadIdx.x;
    if (blockIdx.x < K_CODES / 4) {
        const int w = tid >> 6, lane = tid & 63;
        const int row = blockIdx.x * 4 + w;
        const float* src = cb + (size_t)row * DIM + lane * 8;
        float4 a = *(const float4*)(src);
        float4 b = *(const float4*)(src + 4);
        float ns = a.x * a.x + a.y * a.y + a.z * a.z + a.w * a.w
                 + b.x * b.x + b.y * b.y + b.z * b.z + b.w * b.w;
        const float S = 8192.0f;                 // exact power of 2
        int lo = 0, hi = 0;
        lo = pk8<false>(a.x * S, a.y * S, lo); lo = pk8<true>(a.z * S, a.w * S, lo);
        hi = pk8<false>(b.x * S, b.y * S, hi); hi = pk8<true>(b.z * S, b.w * S, hi);
        *(int2*)(cb8 + (size_t)row * DIM + lane * 8) = make_int2(lo, hi);
        for (int m = 32; m; m >>= 1) ns += __shfl_down(ns, m, 64);
        if (lane == 0) enorm[row] = S * ns;      // 8192 * ||e||^2 (f32-exact norm)
    } else {
        size_t i = ((size_t)(blockIdx.x - K_CODES / 4) * 256 + tid) * 8;
        float4 a = *(const float4*)(z + i);
        float4 b = *(const float4*)(z + i + 4);
        int lo = 0, hi = 0;
        lo = pk8<false>(a.x, a.y, lo); lo = pk8<true>(a.z, a.w, lo);
        hi = pk8<false>(b.x, b.y, hi); hi = pk8<true>(b.z, b.w, hi);
        *(int2*)(z8 + i) = make_int2(lo, hi);
    }
}

// ---- kernel 2: MX-fp8 GEMM (128x128, 4 waves) + packed-argmin ----------
__global__ __launch_bounds__(256, 2) void gemm_argmin(
    const unsigned char* __restrict__ z8, const unsigned char* __restrict__ cbb,
    const float* __restrict__ enorm, unsigned int* __restrict__ candV)
{
    __shared__ alignas(32) unsigned char As[2 * BM * BK];  // 32 KB dbuf
    __shared__ alignas(32) unsigned char Bs[2 * BN * BK];  // 32 KB dbuf
    __shared__ float Es[BN];
    __shared__ unsigned int cU[BM][2];

    const int tid = threadIdx.x;
    const int lane = tid & 63;
    const int w = tid >> 6;             // 0..3
    // XCD remap: b&7 = XCD; XCD owns mtiles [xcd*16,xcd*16+16) (1MB A
    // slice, L2-hot); ktile advances every 128 blocks.
    const int b = blockIdx.x;
    const int xcd = b & 7;
    const int idx = b >> 3;             // 0..1023
    const int ktile = idx >> 4;         // 0..63
    const int mtile = xcd * 16 + (idx & 15);
    const int mbase = mtile * BM;
    const int nbase = ktile * BN;

    if (tid < BN) Es[tid] = enorm[nbase + tid];

    f32x4 acc[16];
#pragma unroll
    for (int i = 0; i < 16; ++i) acc[i] = (f32x4){0.f, 0.f, 0.f, 0.f};

    const int rA = lane >> 3;           // row within 8-row chunk
    const int jG = ((lane & 7) ^ rA) * 16;  // pre-swizzled global 16B chunk
    const int quad = lane >> 4;
    const int l15 = lane & 15;
    const int sw = l15 & 7;
    const int rw = (w >> 1) * 64;       // wave row quadrant
    const int cw = (w & 1) * 64;        // wave col quadrant
    // Chunks c0=(2q)^sw, c1=c0^1 = one aligned 32B block (R3-proven: the
    // per-lane half-swap is identical for A and B -> dot product exact).
    const int t32 = ((quad << 1) ^ (sw & 6)) * 16;

    // Exactly 8 gload_lds per thread per STAGE (vmcnt bookkeeping).
#define STAGE(buf, dt_) do {                                                  \
    _Pragma("unroll")                                                         \
    for (int i_ = 0; i_ < 4; ++i_) {                                          \
        int c_ = w * 4 + i_;                                                  \
        int row_ = c_ * 8 + rA;                                               \
        int col_ = (dt_) * BK + jG;                                           \
        gload_lds(z8 + (size_t)(mbase + row_) * DIM + col_,                   \
                  As + (buf) * (BM * BK) + c_ * 1024 + lane * 16);            \
        gload_lds(cbb + (size_t)(nbase + row_) * DIM + col_,                  \
                  Bs + (buf) * (BN * BK) + c_ * 1024 + lane * 16);            \
    } } while (0)

    STAGE(0, 0);
    __syncthreads();   // full drain: buf0 ready, vmcnt bookkeeping = 0

#pragma unroll 1
    for (int dt = 0; dt < 4; ++dt) {
        const int cur = dt & 1;
        if (dt < 3) {
            STAGE(cur ^ 1, dt + 1);      // 8 loads, stay in flight
            asm volatile("s_waitcnt vmcnt(8)" ::: "memory");  // prev stage landed
        } else {
            asm volatile("s_waitcnt vmcnt(0)" ::: "memory");  // last stage landed
        }
        __builtin_amdgcn_sched_barrier(0);
        __builtin_amdgcn_s_barrier();    // all waves: buf[cur] fully in LDS
        const unsigned char* Ab = As + cur * (BM * BK);
        const unsigned char* Bb = Bs + cur * (BN * BK);
        __builtin_amdgcn_s_setprio(1);
#pragma unroll
        for (int h = 0; h < 2; ++h) {    // 2 B frags live at a time
            i32x8 bf0 = *(const i32x8*)(Bb + (cw + (h * 2 + 0) * 16 + l15) * BK + t32);
            i32x8 bf1 = *(const i32x8*)(Bb + (cw + (h * 2 + 1) * 16 + l15) * BK + t32);
#pragma unroll
            for (int rf = 0; rf < 4; ++rf) {
                i32x8 a = *(const i32x8*)(Ab + (rw + rf * 16 + l15) * BK + t32);
                acc[rf * 4 + h * 2 + 0] = __builtin_amdgcn_mfma_scale_f32_16x16x128_f8f6f4(
                    a, bf0, acc[rf * 4 + h * 2 + 0],
                    0, 0, 0, 0x7F7F7F7F, 0, 0x7F7F7F7F);
                acc[rf * 4 + h * 2 + 1] = __builtin_amdgcn_mfma_scale_f32_16x16x128_f8f6f4(
                    a, bf1, acc[rf * 4 + h * 2 + 1],
                    0, 0, 0, 0x7F7F7F7F, 0, 0x7F7F7F7F);
            }
        }
        __builtin_amdgcn_s_setprio(0);
        // reads of buf[cur] are complete (consumed by MFMAs above) before
        // this barrier; next iter's STAGE overwrite is ordered after it.
        __builtin_amdgcn_s_barrier();
        __builtin_amdgcn_sched_barrier(0);
    }
#undef STAGE

    // epilogue: per-row argmin over this tile's 128 cols.
    // C/D layout: col = lane&15, row = quad*4 + reg.
    // Packed key: monotone-uint(dist), low 13 bits = global code index.
    float es[4];
#pragma unroll
    for (int cf = 0; cf < 4; ++cf) es[cf] = Es[cw + cf * 16 + l15];

#pragma unroll
    for (int rf = 0; rf < 4; ++rf) {
#pragma unroll
        for (int r = 0; r < 4; ++r) {
            float bv = 3.4e38f; int bi = 0;
#pragma unroll
            for (int cf = 0; cf < 4; ++cf) {
                int col = cw + cf * 16 + l15;
                float dist = fmaf(-2.0f, acc[rf * 4 + cf][r], es[cf]);
                if (dist < bv) { bv = dist; bi = col; }  // strict <: low col on tie
            }
            unsigned u = __builtin_bit_cast(unsigned, bv);
            u ^= ((unsigned)(((int)u) >> 31)) | 0x80000000u;
            unsigned key = (u & 0xFFFFE000u) | (unsigned)(nbase + bi);
#pragma unroll
            for (int m = 1; m < 16; m <<= 1) {
                unsigned o = __shfl_xor(key, m, 64);
                key = o < key ? o : key;
            }
            if (l15 == 0) cU[rw + rf * 16 + quad * 4 + r][w & 1] = key;
        }
    }
    __syncthreads();
    if (tid < BM) {
        unsigned k0 = cU[tid][0], k1 = cU[tid][1];
        // [ktile][row] layout: 128 consecutive ints per block = full lines
        candV[(size_t)ktile * M_ROWS + mbase + tid] = k0 < k1 ? k0 : k1;
    }
}

// ---- kernel 3: candidate-reduce + gather + ST output -------------------
// 4 waves/block, wave owns a row/iter: umin over the 64 packed candidates
// (lane = ktile), then 128 float4 slots. Loss partial per block.
__global__ __launch_bounds__(256) void gather_out(
    const float* __restrict__ z, const float* __restrict__ cb,
    const unsigned int* __restrict__ candV, float* __restrict__ out,
    float* __restrict__ partials)
{
    __shared__ float red[4];
    const int tid = threadIdx.x;
    const int w = tid >> 6, lane = tid & 63;
    float lsum = 0.f;
#pragma unroll
    for (int it = 0; it < M_ROWS / (GB_BLOCKS * 4); ++it) {
        int row = (it * GB_BLOCKS + blockIdx.x) * 4 + w;
        unsigned key = candV[(size_t)lane * M_ROWS + row];
#pragma unroll
        for (int m = 1; m < 64; m <<= 1) {
            unsigned o = __shfl_xor(key, m, 64);
            key = o < key ? o : key;
        }
        int k = (int)(key & 8191u);
#pragma unroll
        for (int j = 0; j < 2; ++j) {
            int slot = lane + j * 64;
            float4 zv = ((const float4*)(z + (size_t)row * DIM))[slot];
            float4 cv = ((const float4*)(cb + (size_t)k * DIM))[slot];
            float dx = cv.x - zv.x, dy = cv.y - zv.y;
            float dz2 = cv.z - zv.z, dw = cv.w - zv.w;
            float4 o = {zv.x + dx, zv.y + dy, zv.z + dz2, zv.w + dw};  // z + sg(zq-z)
            ((float4*)(out + (size_t)row * DIM))[slot] = o;
            lsum += dx * dx + dy * dy + dz2 * dz2 + dw * dw;
        }
    }
    for (int m = 32; m; m >>= 1) lsum += __shfl_down(lsum, m, 64);
    if (lane == 0) red[w] = lsum;
    __syncthreads();
    if (tid == 0) partials[blockIdx.x] = (red[0] + red[1]) + (red[2] + red[3]);
}

// ---- kernel 4: final loss reduction (1024 partials -> scalar) ----------
__global__ __launch_bounds__(256) void reduce_loss(
    const float* __restrict__ partials, float* __restrict__ lossOut)
{
    __shared__ float red[4];
    const int tid = threadIdx.x;
    float s = 0.f;
#pragma unroll
    for (int i = 0; i < GB_BLOCKS / 256; ++i) s += partials[i * 256 + tid];
    for (int m = 32; m; m >>= 1) s += __shfl_down(s, m, 64);
    if ((tid & 63) == 0) red[tid >> 6] = s;
    __syncthreads();
    if (tid == 0)
        lossOut[0] = ((red[0] + red[1]) + (red[2] + red[3])) * (1.1f / (float)OUT0_SIZE);
}

extern "C" void kernel_launch(void* const* d_in, const int* in_sizes, int n_in,
                              void* d_out, int out_size, void* d_ws, size_t ws_size,
                              hipStream_t stream) {
    const float* z = (const float*)d_in[0];     // 16*1024*512
    const float* cb = (const float*)d_in[1];    // 8192*512
    float* out = (float*)d_out;                 // 8388608 + 1
    char* ws = (char*)d_ws;

    // ws layout (bytes)
    unsigned char* z8   = (unsigned char*)(ws);               //  8,388,608
    unsigned char* cb8  = (unsigned char*)(ws + 8388608);     //  4,194,304
    float* enorm        = (float*)(ws + 12582912);            //     32,768
    unsigned int* candV = (unsigned int*)(ws + 12615680);     //  4,194,304
    float* partials     = (float*)(ws + 16809984);            //      4,096

    convert_all<<<K_CODES / 4 + M_ROWS * DIM / 2048, 256, 0, stream>>>(
        z, cb, z8, cb8, enorm);
    gemm_argmin<<<NT * (M_ROWS / BM), 256, 0, stream>>>(z8, cb8, enorm, candV);
    gather_out<<<GB_BLOCKS, 256, 0, stream>>>(z, cb, candV, out, partials);
    reduce_loss<<<1, 256, 0, stream>>>(partials, out + OUT0_SIZE);
}